// Round 1
// baseline (204.609 us; speedup 1.0000x reference)
//
#include <hip/hip_runtime.h>
#include <hip/hip_bf16.h>
#include <cstdint>
#include <cstddef>

#define B_ROWS 16384
#define D_DIM  256
#define TEMP_INV 14.285714285714286f   // 1/0.07

#define BM 128
#define BN 128

using frag_cd = __attribute__((ext_vector_type(4))) float;   // 4 fp32
using i32x4   = __attribute__((ext_vector_type(4))) int;     // one 16B chunk
using i32x8   = __attribute__((ext_vector_type(8))) int;     // 32B f8f6f4 operand

// ---------------------------------------------------------------------------
// fp8 operand storage layout (R17): fragment-major, so the GEMM loads operands
// directly global -> VGPR with perfectly coalesced dwordx4 (no LDS, no barriers).
//
// For a matrix [16384][256] fp8: row group g = row>>4, r = row&15; k-byte
// kappa: kt = kappa>>7, chunk c = (kappa&127)>>4, h = c>>2, q = c&3, b = kappa&15.
// byte offset = g*4096 + kt*2048 + h*1024 + q*256 + r*16 + b.
//
// MFMA 16x16x128 fp8 fragment (verified by the previous LDS kernel, absmax=0):
// lane (quad,l15) holds 16B chunks c=quad (h[0]) and c=quad+4 (h[1]) of row l15's
// 128B kt-slab. With this layout that is exactly:
//     h = 0/1 load at  base + g*4096 + kt*2048 + h*1024 + lane*16
// i.e. one contiguous 1KB wave load per fragment half.
// ---------------------------------------------------------------------------

// Kernel 1: L2-normalize q,d rows -> fp8 e4m3 (HW cvt_pk, RNE), stored in the
// fragment-major swizzled layout above; diag[i] exact fp32.
// Also zero-initializes row_sums/col_sums/out (replaces memset dispatches).
__global__ __launch_bounds__(256) void norm_diag_kernel(
    const float* __restrict__ q, const float* __restrict__ d,
    unsigned int* __restrict__ qn, unsigned int* __restrict__ dn,
    float* __restrict__ diag,
    float* __restrict__ row_sums, float* __restrict__ col_sums,
    float* __restrict__ out) {
    const int b = blockIdx.x;
    if (b < 64)            row_sums[b * 256 + threadIdx.x] = 0.0f;
    else if (b < 128)      col_sums[(b - 64) * 256 + threadIdx.x] = 0.0f;
    else if (b == 128 && threadIdx.x == 0) out[0] = 0.0f;

    const int row  = b * 4 + (threadIdx.x >> 6);
    const int lane = threadIdx.x & 63;

    const float4 qv = ((const float4*)(q + (size_t)row * D_DIM))[lane];
    const float4 dv = ((const float4*)(d + (size_t)row * D_DIM))[lane];

    float qss = qv.x*qv.x + qv.y*qv.y + qv.z*qv.z + qv.w*qv.w;
    float dss = dv.x*dv.x + dv.y*dv.y + dv.z*dv.z + dv.w*dv.w;
    float qd  = qv.x*dv.x + qv.y*dv.y + qv.z*dv.z + qv.w*dv.w;
#pragma unroll
    for (int off = 32; off; off >>= 1) {
        qss += __shfl_down(qss, off);
        dss += __shfl_down(dss, off);
        qd  += __shfl_down(qd,  off);
    }
    qss = __shfl(qss, 0);
    dss = __shfl(dss, 0);
    qd  = __shfl(qd,  0);

    const float qinv = 1.0f / fmaxf(sqrtf(qss), 1e-12f);
    const float dinv = 1.0f / fmaxf(sqrtf(dss), 1e-12f);

    // Pack 4 normalized values (kappa = 4*lane .. 4*lane+3) -> 4 fp8 e4m3 bytes.
    int qp = 0, dp = 0;
    qp = __builtin_amdgcn_cvt_pk_fp8_f32(qv.x * qinv, qv.y * qinv, qp, false);
    qp = __builtin_amdgcn_cvt_pk_fp8_f32(qv.z * qinv, qv.w * qinv, qp, true);
    dp = __builtin_amdgcn_cvt_pk_fp8_f32(dv.x * dinv, dv.y * dinv, dp, false);
    dp = __builtin_amdgcn_cvt_pk_fp8_f32(dv.z * dinv, dv.w * dinv, dp, true);

    // Swizzled word index: g*1024 + kt*512 + h*256 + q*64 + r*4 + (lane&3)
    // with kt = lane>>5, h = (lane>>4)&1, q = (lane>>2)&3 (verified: kappa==4*lane).
    const int g = row >> 4;
    const int widx = (g << 10) | ((lane >> 5) << 9) | (((lane >> 4) & 1) << 8)
                   | (((lane >> 2) & 3) << 6) | ((row & 15) << 2) | (lane & 3);
    qn[widx] = (unsigned int)qp;
    dn[widx] = (unsigned int)dp;

    if (lane == 0) diag[row] = qd * qinv * dinv * TEMP_INV;
}

// Kernel 2 (R17): 128x128 tile of sim = qn . dn^T in fp8 e4m3, fused exp sums.
// NO LDS, NO barriers: operands load directly global->VGPR from the
// fragment-major layout (each fragment half = one coalesced 1KB dwordx4 load).
// Rationale: R14-R16 counters showed gemm wall ~= SUM of MFMA(24%) + LDS(~44%)
// + VALU(~20%) pipes — blocks are barrier-phase-locked so pipes never overlap.
// Removing LDS+barriers (a) deletes the LDS pipe term outright, (b) makes waves
// independent so they self-stagger and MFMA/VALU/TRANS/VMEM overlap. Operand
// panels (8 MB total fp8) are L2/L3-resident; per-block register traffic 128KB
// is served by L1/L2.
__global__ __launch_bounds__(256, 4) void gemm_lse_kernel(
    const unsigned char* __restrict__ qn, const unsigned char* __restrict__ dn,
    float* __restrict__ row_sums, float* __restrict__ col_sums) {
    const int t    = threadIdx.x;
    const int lane = t & 63;
    const int w    = t >> 6;
    const int l15  = lane & 15;
    const int quad = lane >> 4;
    const int m0   = (w >> 1) * 64;
    const int n0   = (w & 1) * 64;

    // XCD swizzle: id -> (bx, by)
    const int id  = blockIdx.x;
    const int xcd = id & 7;
    const int j   = id >> 3;
    const int bx  = (xcd << 4) | (j & 15);
    const int by  = j >> 4;
    const int rowBase = by * BM;
    const int colBase = bx * BN;

    // Fragment base pointers: group (rowBase+m0)/16, +mi advances one group (4KB).
    const unsigned char* aB = qn + ((size_t)((rowBase + m0) >> 4) << 12) + lane * 16;
    const unsigned char* bB = dn + ((size_t)((colBase + n0) >> 4) << 12) + lane * 16;

    frag_cd acc[4][4];
#pragma unroll
    for (int i = 0; i < 4; ++i)
#pragma unroll
        for (int jj = 0; jj < 4; ++jj)
            acc[i][jj] = (frag_cd){0.0f, 0.0f, 0.0f, 0.0f};

    union OpU { i32x8 v; i32x4 h[2]; };

#pragma unroll
    for (int kt = 0; kt < 2; ++kt) {
        // All 4 B operands resident; A streamed one frag at a time (low reg peak).
        OpU b8[4];
#pragma unroll
        for (int ni = 0; ni < 4; ++ni) {
            b8[ni].h[0] = *(const i32x4*)(bB + (size_t)ni * 4096 + kt * 2048);
            b8[ni].h[1] = *(const i32x4*)(bB + (size_t)ni * 4096 + kt * 2048 + 1024);
        }
#pragma unroll
        for (int mi = 0; mi < 4; ++mi) {
            OpU a8;
            a8.h[0] = *(const i32x4*)(aB + (size_t)mi * 4096 + kt * 2048);
            a8.h[1] = *(const i32x4*)(aB + (size_t)mi * 4096 + kt * 2048 + 1024);
#pragma unroll
            for (int ni = 0; ni < 4; ++ni)
                acc[mi][ni] = __builtin_amdgcn_mfma_scale_f32_16x16x128_f8f6f4(
                    a8.v, b8[ni].v, acc[mi][ni],
                    0, 0,                      // cbsz=FP8 e4m3, blgp=FP8 e4m3
                    0, 0x7F7F7F7F,             // opsel_a, scale_a = 1.0 per block
                    0, 0x7F7F7F7F);            // opsel_b, scale_b = 1.0 per block
        }
    }

    // ---- Epilogue ----
    // C frag layout (shape-determined — m89/m127/m128):
    // lane holds col = n0+ni*16+l15, row = m0+mi*16+quad*4+r.
    // e = exp(sim - 1/T) = 2^(acc*C - C), C = (1/T)*log2(e). Packed float4 math.
    const float C2 = TEMP_INV * 1.44269504088896f;
    union { frag_cd v[4]; float f[16]; } rvu;
    frag_cd cv4[4];
#pragma unroll
    for (int i = 0; i < 4; ++i) {
        rvu.v[i] = (frag_cd){0.0f, 0.0f, 0.0f, 0.0f};
        cv4[i]   = (frag_cd){0.0f, 0.0f, 0.0f, 0.0f};
    }
#pragma unroll
    for (int mi = 0; mi < 4; ++mi)
#pragma unroll
        for (int ni = 0; ni < 4; ++ni) {
            const frag_cd tt = acc[mi][ni] * C2 - C2;   // v_pk_fma_f32 x2
            frag_cd e;
#pragma unroll
            for (int r = 0; r < 4; ++r) e[r] = __builtin_amdgcn_exp2f(tt[r]);
            rvu.v[mi] += e;   // row partials (sum over ni)
            cv4[ni]   += e;   // col partials (sum over mi)
        }
    float cv[4];
#pragma unroll
    for (int ni = 0; ni < 4; ++ni)
        cv[ni] = (cv4[ni][0] + cv4[ni][1]) + (cv4[ni][2] + cv4[ni][3]);

    // Row butterfly all-reduce over the 16 lanes of each quad; end: f[0] <-> p = l15.
#pragma unroll
    for (int s = 0; s < 4; ++s) {
        const bool b = (l15 >> s) & 1;
#pragma unroll
        for (int i = 0; i < (8 >> s); ++i) {
            const float a0 = rvu.f[2 * i], a1 = rvu.f[2 * i + 1];
            const float keep = b ? a1 : a0;
            const float send = b ? a0 : a1;
            rvu.f[i] = keep + __shfl_xor(send, 1 << s);
        }
    }
    atomicAdd(&row_sums[rowBase + m0 + (l15 >> 2) * 16 + quad * 4 + (l15 & 3)], rvu.f[0]);

    // Col butterfly all-reduce over the 4 quads; end: cv[0] <-> ni = quad.
#pragma unroll
    for (int s = 0; s < 2; ++s) {
        const bool b = (quad >> s) & 1;
#pragma unroll
        for (int i = 0; i < (2 >> s); ++i) {
            const float a0 = cv[2 * i], a1 = cv[2 * i + 1];
            const float keep = b ? a1 : a0;
            const float send = b ? a0 : a1;
            cv[i] = keep + __shfl_xor(send, 16 << s);
        }
    }
    atomicAdd(&col_sums[colBase + n0 + quad * 16 + l15], cv[0]);
}

// Kernel 3 (parallel): each block reduces 256 rows, atomicAdd into zeroed out[0].
__global__ __launch_bounds__(256) void finalize_kernel(
    const float* __restrict__ rs, const float* __restrict__ cs,
    const float* __restrict__ dg, float* __restrict__ out) {
    const int i = blockIdx.x * 256 + threadIdx.x;
    float s = logf(rs[i]) + logf(cs[i]) - 2.0f * dg[i];
#pragma unroll
    for (int off = 32; off; off >>= 1) s += __shfl_down(s, off);
    __shared__ float buf[4];
    if ((threadIdx.x & 63) == 0) buf[threadIdx.x >> 6] = s;
    __syncthreads();
    if (threadIdx.x == 0) {
        float tot = (buf[0] + buf[1] + buf[2] + buf[3]) / (2.0f * B_ROWS);
        if (blockIdx.x == 0) tot += TEMP_INV;   // undo the fixed exp shift
        atomicAdd(out, tot);
    }
}

extern "C" void kernel_launch(void* const* d_in, const int* in_sizes, int n_in,
                              void* d_out, int out_size, void* d_ws, size_t ws_size,
                              hipStream_t stream) {
    const float* q = (const float*)d_in[0];
    const float* d = (const float*)d_in[1];
    float* out = (float*)d_out;

    char* ws = (char*)d_ws;
    unsigned char* qn = (unsigned char*)ws;                         // 4 MB fp8 (swizzled)
    unsigned char* dn = qn + (size_t)B_ROWS * D_DIM;                // 4 MB fp8 (swizzled)
    float* row_sums = (float*)(ws + 2 * (size_t)B_ROWS * D_DIM);
    float* col_sums = row_sums + B_ROWS;
    float* diag     = col_sums + B_ROWS;

    norm_diag_kernel<<<B_ROWS / 4, 256, 0, stream>>>(
        q, d, (unsigned int*)qn, (unsigned int*)dn, diag, row_sums, col_sums, out);
    gemm_lse_kernel<<<(B_ROWS / BM) * (B_ROWS / BN), 256, 0, stream>>>(
        qn, dn, row_sums, col_sums);
    finalize_kernel<<<B_ROWS / 256, 256, 0, stream>>>(row_sums, col_sums, diag, out);
}